// Round 15
// baseline (289.397 us; speedup 1.0000x reference)
//
#include <hip/hip_runtime.h>

typedef __bf16 bf16x8 __attribute__((ext_vector_type(8)));
typedef float f32x4 __attribute__((ext_vector_type(4)));

#define T_LEN 200
#define NB 4096

__device__ __forceinline__ f32x4 mfma16(bf16x8 a, bf16x8 b, f32x4 c) {
    return __builtin_amdgcn_mfma_f32_16x16x32_bf16(a, b, c, 0, 0, 0);
}
// raw v_rcp_f32 (1 ulp) transcendentals; saturation exact (rcp(inf)=0)
__device__ __forceinline__ float sigf(float x) {
    return __builtin_amdgcn_rcpf(1.0f + __expf(-x));
}
__device__ __forceinline__ float tanh_fast(float x) {
    return 1.0f - 2.0f * __builtin_amdgcn_rcpf(__expf(2.0f * x) + 1.0f);
}

// ---- RNE bf16 pack of two floats -> one dword ----
__device__ __forceinline__ unsigned packRNE2(float a, float b) {
    unsigned ha = (unsigned)__builtin_bit_cast(unsigned short, (__bf16)a);
    unsigned hb = (unsigned)__builtin_bit_cast(unsigned short, (__bf16)b);
    return ha | (hb << 16);
}
// ---- RNE hi-only publish (h-state exchanges) ----
__device__ __forceinline__ void publish_hi(unsigned short* hp, float v) {
    __bf16 h = (__bf16)v;
    *hp = __builtin_bit_cast(unsigned short, h);
}

struct Frag { bf16x8 hi, lo; };
__device__ __forceinline__ Frag make_frag(f32x4 a, f32x4 b) {
    Frag f;
    #pragma unroll
    for (int j = 0; j < 4; j++) {
        float v = a[j]; __bf16 h = (__bf16)v;
        f.hi[j] = h; f.lo[j] = (__bf16)(v - (float)h);
    }
    #pragma unroll
    for (int j = 0; j < 4; j++) {
        float v = b[j]; __bf16 h = (__bf16)v;
        f.hi[4 + j] = h; f.lo[4 + j] = (__bf16)(v - (float)h);
    }
    return f;
}
__device__ __forceinline__ bf16x8 load_w(const float* p) {   // W: bf16 RNE hi only
    f32x4 a = *(const f32x4*)p, b = *(const f32x4*)(p + 4);
    bf16x8 w;
    #pragma unroll
    for (int j = 0; j < 4; j++) { w[j] = (__bf16)a[j]; w[4 + j] = (__bf16)b[j]; }
    return w;
}

// R14 structure + cross-barrier x prefetch (double-buffered sX, staged in S0,
// fragment-prefetched in S1 so S0 has no x ds_read on the critical path).
// 8 waves: 0-3 GRU (G), 4-7 AUGRU (A). AUGRU pipelined one step.
// LDS hazards (producer -> consumer crosses >=1 barrier):
//   sX[p]: W by G in S0(t) [x(t+1), p=(t+1)&1], R by all in S1(t)   [b_mid];
//          p reused at S0(t+2) — last read S1(t), 2 barriers earlier ✓
//   sHG : W by G in S0(t), R by G in S1(t)                           [b_mid]
//   sScore[p]: W by G(wg0) in S1(t) (p=t&1, pre-sigmoided), R by A in S0(t+1) [b_end]
//   sHA : W by A in S0(t), R by A in S1(t)                           [b_mid]
//   sRH : W by A in S1(t), R by A in S0(t+1)/epilogue                [b_end]
__global__ __launch_bounds__(512, 2)
void dien_fused(const int* __restrict__ u_idx, const int* __restrict__ i_idx,
                const int* __restrict__ seq, const float* __restrict__ item_emb,
                const float* __restrict__ user_bias, const float* __restrict__ item_bias,
                const float* __restrict__ gw_ih, const float* __restrict__ gb_ih,
                const float* __restrict__ gw_hh, const float* __restrict__ gb_hh,
                const float* __restrict__ attn_w, const float* __restrict__ attn_b,
                const float* __restrict__ wr_w, const float* __restrict__ wr_b,
                const float* __restrict__ wz_w, const float* __restrict__ wz_b,
                const float* __restrict__ wh_w, const float* __restrict__ wh_b,
                const float* __restrict__ aux_w, const float* __restrict__ aux_b,
                float* __restrict__ out)
{
    __shared__ int sSeq[16][T_LEN];
    __shared__ __align__(16) float sTP[16][64];
    __shared__ __align__(16) unsigned short sHGhi[16][72];
    __shared__ __align__(16) unsigned short sHAhi[16][72];
    __shared__ __align__(16) unsigned short sRHhi[16][72];
    __shared__ __align__(16) unsigned short sXhi[2][16][72];
    __shared__ float sScore[2][16];
    __shared__ float sParts[16][4];

    const int tid  = threadIdx.x;
    const int wave = tid >> 6;           // 0..7
    const int lane = tid & 63;
    const int c    = lane & 15;
    const int q    = lane >> 4;
    const bool isG = (wave < 4);
    const int wg   = wave & 3;
    const int dglob = wg * 16 + c;
    const int row0 = blockIdx.x * 16;

    // ---- stage seq indices ----
    for (int i = tid; i < 16 * T_LEN; i += 512) {
        int b = i / T_LEN, t = i - b * T_LEN;
        sSeq[b][t] = seq[(row0 + b) * T_LEN + t];
    }

    // ---- fm1 ----
    if (tid < 16) {
        int b = row0 + tid;
        out[b] = user_bias[u_idx[b]] + item_bias[i_idx[b]];
    }

    // ---- target_proj (16x64 fp32), threads 0..255 ----
    if (tid < 256) {
        int b  = tid >> 4;
        int d0 = (tid & 15) * 4;
        const float* erow = item_emb + (long)i_idx[row0 + b] * 64;
        float e[64];
        #pragma unroll
        for (int k4 = 0; k4 < 16; k4++) {
            f32x4 v = *(const f32x4*)(erow + k4 * 4);
            #pragma unroll
            for (int j = 0; j < 4; j++) e[k4 * 4 + j] = v[j];
        }
        #pragma unroll
        for (int dd = 0; dd < 4; dd++) {
            int d = d0 + dd;
            const float* wrow = attn_w + d * 64;
            float s = attn_b[d];
            #pragma unroll
            for (int k4 = 0; k4 < 16; k4++) {
                f32x4 wv = *(const f32x4*)(wrow + k4 * 4);
                #pragma unroll
                for (int j = 0; j < 4; j++) s += e[k4 * 4 + j] * wv[j];
            }
            sTP[b][d] = s;
        }
    }

    // ---- zero ha exchange buffer; prime sX[0] with x(0) ----
    for (int i = tid; i < 16 * 72; i += 512) sHAhi[0][i] = 0;
    const int xrow = wg * 4 + (lane >> 4);   // producer row (G)
    const int xch  = lane & 15;              // 4-float chunk within row
    if (isG) {
        const float* p = item_emb + (long)seq[(row0 + xrow) * T_LEN + 0] * 64 + xch * 4;
        f32x4 v = *(const f32x4*)p;
        *(uint2*)&sXhi[0][xrow][xch * 4] =
            make_uint2(packRNE2(v[0], v[1]), packRNE2(v[2], v[3]));
    }
    __syncthreads();

    // ---- register-resident weights (bf16-hi RNE), unioned across groups ----
    // G: W[0..1]=wih_r, W[2..3]=wih_z, W[4..5]=wih_n, W[6..7]=whh_r, W[8..9]=whh_z, W[10..11]=whh_n
    // A: W[0..1]=wrx, W[2..3]=wrh, W[4..5]=wzx, W[6..7]=wzh, W[8..9]=whx, W[10..11]=whhat
    bf16x8 W[12];
    if (isG) {
        #pragma unroll
        for (int g = 0; g < 3; g++)
            #pragma unroll
            for (int s = 0; s < 2; s++) {
                W[g * 2 + s]     = load_w(gw_ih + (g * 64 + dglob) * 64 + s * 32 + q * 8);
                W[6 + g * 2 + s] = load_w(gw_hh + (g * 64 + dglob) * 64 + s * 32 + q * 8);
            }
    } else {
        #pragma unroll
        for (int s = 0; s < 2; s++) {
            const int fo = dglob * 128 + s * 32 + q * 8;
            W[0 + s]  = load_w(wr_w + fo);
            W[2 + s]  = load_w(wr_w + fo + 64);
            W[4 + s]  = load_w(wz_w + fo);
            W[6 + s]  = load_w(wz_w + fo + 64);
            W[8 + s]  = load_w(wh_w + fo);
            W[10 + s] = load_w(wh_w + fo + 64);
        }
    }

    float bA, bB, bC, bD;
    if (isG) {
        bA = gb_ih[dglob] + gb_hh[dglob];
        bB = gb_ih[64 + dglob] + gb_hh[64 + dglob];
        bC = gb_ih[128 + dglob];
        bD = gb_hh[128 + dglob];
    } else {
        bA = wr_b[dglob];
        bB = wz_b[dglob];
        bC = wh_b[dglob];
        bD = 0.0f;
    }
    const f32x4 vbA = {bA, bA, bA, bA};
    const f32x4 vbB = {bB, bB, bB, bB};
    const f32x4 vbC = {bC, bC, bC, bC};
    const f32x4 vbD = {bD, bD, bD, bD};
    const float auxwc = aux_w[dglob];

    // TP as B-fragment (G only), hi/lo (score feeds sigmoid; keep accurate)
    Frag tpB0, tpB1;
    if (isG) {
        tpB0 = make_frag(*(const f32x4*)&sTP[c][q * 8], *(const f32x4*)&sTP[c][q * 8 + 4]);
        tpB1 = make_frag(*(const f32x4*)&sTP[c][32 + q * 8], *(const f32x4*)&sTP[c][32 + q * 8 + 4]);
    }

    // ---- state ----
    float hst[4] = {0.f, 0.f, 0.f, 0.f};   // G: hg(t); A: ha(t-1)
    bf16x8 fr0, fr1;                        // G: hg(t-1) hi-frags; A: scratch
    #pragma unroll
    for (int j = 0; j < 8; j++) { fr0[j] = (__bf16)0.f; fr1[j] = (__bf16)0.f; }
    f32x4 aAR = vbA, aAZ = vbB, aAH = vbC;  // A: accs for current tau
    float z_c[4] = {0.f, 0.f, 0.f, 0.f};

    // ---- preloads: x(0) frags from sX[0]; xg = x(1) (G) ----
    bf16x8 x0 = *(const bf16x8*)&sXhi[0][c][q * 8];
    bf16x8 x1 = *(const bf16x8*)&sXhi[0][c][32 + q * 8];
    f32x4 xg = {0.f, 0.f, 0.f, 0.f};
    if (isG) {
        int t1 = (1 < T_LEN) ? 1 : 0;
        xg = *(const f32x4*)(item_emb + (long)sSeq[xrow][t1] * 64 + xch * 4);
    }

    for (int t = 0; t < T_LEN; t++) {
        // ================= Section 0 =================
        if (isG) {
            // stage x(t+1) into alternate buffer (no S0 readers of sX)
            *(uint2*)&sXhi[(t + 1) & 1][xrow][xch * 4] =
                make_uint2(packRNE2(xg[0], xg[1]), packRNE2(xg[2], xg[3]));
            // issue load of x(t+2) — full-step window
            int tn = (t + 2 < T_LEN) ? t + 2 : T_LEN - 1;
            xg = *(const f32x4*)(item_emb + (long)sSeq[xrow][tn] * 64 + xch * 4);

            f32x4 accR = vbA;
            accR = mfma16(x0, W[0], accR); accR = mfma16(x1, W[1], accR);
            accR = mfma16(fr0, W[6], accR); accR = mfma16(fr1, W[7], accR);
            f32x4 accZ = vbB;
            accZ = mfma16(x0, W[2], accZ); accZ = mfma16(x1, W[3], accZ);
            accZ = mfma16(fr0, W[8], accZ); accZ = mfma16(fr1, W[9], accZ);
            f32x4 accNX = vbC;
            accNX = mfma16(x0, W[4], accNX); accNX = mfma16(x1, W[5], accNX);
            f32x4 accNH = vbD;
            accNH = mfma16(fr0, W[10], accNH); accNH = mfma16(fr1, W[11], accNH);

            #pragma unroll
            for (int i = 0; i < 4; i++) {
                float r = sigf(accR[i]);
                float z = sigf(accZ[i]);
                float n = tanh_fast(accNX[i] + r * accNH[i]);
                float hn = n + z * (hst[i] - n);
                hst[i] = hn;
                publish_hi(&sHGhi[q * 4 + i][dglob], hn);
            }
        } else {
            bf16x8 rh0, rh1;
            if (t > 0) {   // issue reads first; x-MFMAs below cover the latency
                rh0 = *(const bf16x8*)&sRHhi[c][q * 8];
                rh1 = *(const bf16x8*)&sRHhi[c][32 + q * 8];
            }
            // x-parts of step t (independent of the reads)
            f32x4 nAR = vbA;
            nAR = mfma16(x0, W[0], nAR); nAR = mfma16(x1, W[1], nAR);
            f32x4 nAZ = vbB;
            nAZ = mfma16(x0, W[4], nAZ); nAZ = mfma16(x1, W[5], nAZ);
            f32x4 nAH = vbC;
            nAH = mfma16(x0, W[8], nAH); nAH = mfma16(x1, W[9], nAH);
            if (t > 0) {
                aAH = mfma16(rh0, W[10], aAH); aAH = mfma16(rh1, W[11], aAH);
                #pragma unroll
                for (int i = 0; i < 4; i++) {
                    int rr = q * 4 + i;
                    float a = sScore[(t - 1) & 1][rr];   // pre-sigmoided
                    float hh = tanh_fast(aAH[i]);
                    float zz = a * z_c[i];
                    float hv = hst[i] + zz * (hh - hst[i]);
                    hst[i] = hv;
                    publish_hi(&sHAhi[rr][dglob], hv);
                }
            }
            aAR = nAR; aAZ = nAZ; aAH = nAH;
        }

        __syncthreads();  // b_mid

        // ================= Section 1 =================
        if (isG) {
            fr0 = *(const bf16x8*)&sHGhi[c][q * 8];
            fr1 = *(const bf16x8*)&sHGhi[c][32 + q * 8];
            // prefetch x(t+1) frags (independent; covers fr read latency)
            x0 = *(const bf16x8*)&sXhi[(t + 1) & 1][c][q * 8];
            x1 = *(const bf16x8*)&sXhi[(t + 1) & 1][c][32 + q * 8];
            // score(t) = diag(hg(t) . tp^T) via MFMA (hg hi x tp hi/lo)
            f32x4 sc = {0.f, 0.f, 0.f, 0.f};
            sc = mfma16(fr0, tpB0.hi, sc); sc = mfma16(fr0, tpB0.lo, sc);
            sc = mfma16(fr1, tpB1.hi, sc); sc = mfma16(fr1, tpB1.lo, sc);
            if (wg == 0 && (c >> 2) == q) {
                int i = c & 3;
                float d = (i == 0) ? sc[0] : (i == 1) ? sc[1] : (i == 2) ? sc[2] : sc[3];
                sScore[t & 1][c] = sigf(d);
            }
        } else {
            bf16x8 ha0 = *(const bf16x8*)&sHAhi[c][q * 8];
            bf16x8 ha1 = *(const bf16x8*)&sHAhi[c][32 + q * 8];
            // prefetch x(t+1) frags (independent; covers ha read latency)
            x0 = *(const bf16x8*)&sXhi[(t + 1) & 1][c][q * 8];
            x1 = *(const bf16x8*)&sXhi[(t + 1) & 1][c][32 + q * 8];
            aAR = mfma16(ha0, W[2], aAR); aAR = mfma16(ha1, W[3], aAR);
            aAZ = mfma16(ha0, W[6], aAZ); aAZ = mfma16(ha1, W[7], aAZ);
            #pragma unroll
            for (int i = 0; i < 4; i++) {
                float r = sigf(aAR[i]);
                z_c[i]  = sigf(aAZ[i]);
                float rh = r * hst[i];
                publish_hi(&sRHhi[q * 4 + i][dglob], rh);
            }
        }

        __syncthreads();  // b_end
    }

    // ---- epilogue: A finalizes ha(T-1), writes attn_vec ----
    if (!isG) {
        bf16x8 rh0 = *(const bf16x8*)&sRHhi[c][q * 8];
        bf16x8 rh1 = *(const bf16x8*)&sRHhi[c][32 + q * 8];
        aAH = mfma16(rh0, W[10], aAH); aAH = mfma16(rh1, W[11], aAH);
        #pragma unroll
        for (int i = 0; i < 4; i++) {
            int rr = q * 4 + i;
            float a = sScore[(T_LEN - 1) & 1][rr];
            float hh = tanh_fast(aAH[i]);
            float zz = a * z_c[i];
            float hv = hst[i] + zz * (hh - hst[i]);
            out[NB + (row0 + rr) * 64 + dglob] = hv;
        }
    }

    // ---- aux_logits from hg(T-1) (G group) ----
    if (isG) {
        float pa[4];
        #pragma unroll
        for (int i = 0; i < 4; i++) pa[i] = hst[i] * auxwc;
        #pragma unroll
        for (int m = 1; m < 16; m <<= 1) {
            #pragma unroll
            for (int i = 0; i < 4; i++) pa[i] += __shfl_xor(pa[i], m, 64);
        }
        if (c == 0) {
            #pragma unroll
            for (int i = 0; i < 4; i++) sParts[q * 4 + i][wg] = pa[i];
        }
    }
    __syncthreads();
    if (tid < 16) {
        out[NB + NB * 64 + row0 + tid] =
            sParts[tid][0] + sParts[tid][1] + sParts[tid][2] + sParts[tid][3] + aux_b[0];
    }
}

extern "C" void kernel_launch(void* const* d_in, const int* in_sizes, int n_in,
                              void* d_out, int out_size, void* d_ws, size_t ws_size,
                              hipStream_t stream) {
    dien_fused<<<dim3(256), dim3(512), 0, stream>>>(
        (const int*)d_in[0],      // u_idx
        (const int*)d_in[1],      // i_idx
        (const int*)d_in[2],      // seq
        (const float*)d_in[3],    // item_emb
        (const float*)d_in[4],    // user_bias
        (const float*)d_in[5],    // item_bias
        (const float*)d_in[6],    // gru_w_ih
        (const float*)d_in[7],    // gru_b_ih
        (const float*)d_in[8],    // gru_w_hh
        (const float*)d_in[9],    // gru_b_hh
        (const float*)d_in[10],   // attn_w
        (const float*)d_in[11],   // attn_b
        (const float*)d_in[12],   // wr_w
        (const float*)d_in[13],   // wr_b
        (const float*)d_in[14],   // wz_w
        (const float*)d_in[15],   // wz_b
        (const float*)d_in[16],   // wh_w
        (const float*)d_in[17],   // wh_b
        (const float*)d_in[18],   // aux_w
        (const float*)d_in[19],   // aux_b
        (float*)d_out);
}